// Round 1
// baseline (3300.837 us; speedup 1.0000x reference)
//
#include <hip/hip_runtime.h>
#include <math.h>

#define NN 102400          // total nodes
#define BG 1024            // graphs
#define NPG 100            // nodes per graph
#define EPG 1600
#define EE (BG*EPG)        // 1,638,400 edges
#define DD 512
#define EPSN 1e-5f
#define SLOPE 0.1f

// ---------------- setup kernels ----------------

__global__ __launch_bounds__(256) void k_degrees(const int* __restrict__ src,
                                                 const int* __restrict__ dst,
                                                 float* degOut, float* degIn) {
    int e = blockIdx.x * 256 + threadIdx.x;        // grid is exactly EE/256
    atomicAdd(&degOut[src[e]], 1.0f);
    atomicAdd(&degIn[dst[e]], 1.0f);
}

__global__ __launch_bounds__(256) void k_deg_to_c(float* cOut, float* cIn) {
    int i = blockIdx.x * 256 + threadIdx.x;        // grid exactly NN/256
    float a = cOut[i]; a = a < 1.0f ? 1.0f : a;
    cOut[i] = 1.0f / sqrtf(a);
    float b = cIn[i]; b = b < 1.0f ? 1.0f : b;
    cIn[i] = 1.0f / sqrtf(b);
}

__global__ __launch_bounds__(256) void k_build_A(const int* __restrict__ src,
                                                 const int* __restrict__ dst,
                                                 float* __restrict__ A) {
    int e = blockIdx.x * 256 + threadIdx.x;
    int s = src[e], d = dst[e];
    int g = s / NPG;
    int u = s - g * NPG;
    int v = d - g * NPG;                            // dst in same graph by construction
    atomicAdd(&A[(size_t)g * (NPG*NPG) + v * NPG + u], 1.0f);
}

__global__ __launch_bounds__(256) void k_scale_A(float* __restrict__ A,
                                                 const float* __restrict__ cOut,
                                                 const float* __restrict__ cIn) {
    int idx = blockIdx.x * 256 + threadIdx.x;       // grid exactly BG*10000/256
    int g = idx / (NPG*NPG);
    int r = idx - g * (NPG*NPG);
    int v = r / NPG;
    int u = r - v * NPG;
    A[idx] *= cIn[g*NPG + v] * cOut[g*NPG + u];
}

// ---------------- per-graph dense aggregation: msg = A' @ h ----------------
// one block per graph; A' (100x100) cached in LDS for all 16 d-chunks.

#define GG_DC 32

__global__ __launch_bounds__(256) void k_graph_gemm(const float* __restrict__ A,
                                                    const float* __restrict__ h,
                                                    float* __restrict__ msg) {
    __shared__ float As[NPG][108];    // pad 108: f4-aligned rows, tolerable conflicts
    __shared__ float hs[NPG][GG_DC];
    int g = blockIdx.x, tid = threadIdx.x;
    const float* Ag = A + (size_t)g * (NPG*NPG);
    size_t hbase = (size_t)g * NPG * DD;

    for (int i = tid; i < NPG*NPG; i += 256) {
        int v = i / NPG;
        As[v][i - v*NPG] = Ag[i];
    }

    int tx = tid & 7;           // d-quad within 32-col chunk
    int ty = tid >> 3;          // v-quad index: v0 = 4*ty (ty<=24 active)
    int v0 = ty * 4;

    for (int d0 = 0; d0 < DD; d0 += GG_DC) {
        // stage the h chunk via registers (3 loads/thread + 1 for tid<32; 800 f4 total)
        int i0 = tid, i1 = tid + 256, i2 = tid + 512, i3 = tid + 768;
        float4 t0, t1, t2, t3;
        t0 = *(const float4*)&h[hbase + (size_t)(i0 >> 3) * DD + d0 + (i0 & 7) * 4];
        t1 = *(const float4*)&h[hbase + (size_t)(i1 >> 3) * DD + d0 + (i1 & 7) * 4];
        t2 = *(const float4*)&h[hbase + (size_t)(i2 >> 3) * DD + d0 + (i2 & 7) * 4];
        if (tid < 32)
            t3 = *(const float4*)&h[hbase + (size_t)(i3 >> 3) * DD + d0 + (i3 & 7) * 4];
        __syncthreads();   // previous chunk's readers done (also orders As stores)
        *(float4*)&hs[i0 >> 3][(i0 & 7) * 4] = t0;
        *(float4*)&hs[i1 >> 3][(i1 & 7) * 4] = t1;
        *(float4*)&hs[i2 >> 3][(i2 & 7) * 4] = t2;
        if (tid < 32) *(float4*)&hs[i3 >> 3][(i3 & 7) * 4] = t3;
        __syncthreads();

        if (v0 < NPG) {
            float4 acc0 = make_float4(0,0,0,0);
            float4 acc1 = acc0, acc2 = acc0, acc3 = acc0;
            for (int u0 = 0; u0 < NPG; u0 += 4) {   // 25 iterations
                float4 a0 = *(float4*)&As[v0+0][u0];
                float4 a1 = *(float4*)&As[v0+1][u0];
                float4 a2 = *(float4*)&As[v0+2][u0];
                float4 a3 = *(float4*)&As[v0+3][u0];
                float4 h0 = *(float4*)&hs[u0+0][tx*4];
                float4 h1 = *(float4*)&hs[u0+1][tx*4];
                float4 h2 = *(float4*)&hs[u0+2][tx*4];
                float4 h3 = *(float4*)&hs[u0+3][tx*4];
#define GACC(ACC, AV) \
    ACC.x = fmaf(AV.x, h0.x, fmaf(AV.y, h1.x, fmaf(AV.z, h2.x, fmaf(AV.w, h3.x, ACC.x)))); \
    ACC.y = fmaf(AV.x, h0.y, fmaf(AV.y, h1.y, fmaf(AV.z, h2.y, fmaf(AV.w, h3.y, ACC.y)))); \
    ACC.z = fmaf(AV.x, h0.z, fmaf(AV.y, h1.z, fmaf(AV.z, h2.z, fmaf(AV.w, h3.z, ACC.z)))); \
    ACC.w = fmaf(AV.x, h0.w, fmaf(AV.y, h1.w, fmaf(AV.z, h2.w, fmaf(AV.w, h3.w, ACC.w))));
                GACC(acc0, a0) GACC(acc1, a1) GACC(acc2, a2) GACC(acc3, a3)
#undef GACC
            }
            *(float4*)&msg[hbase + (size_t)(v0+0)*DD + d0 + tx*4] = acc0;
            *(float4*)&msg[hbase + (size_t)(v0+1)*DD + d0 + tx*4] = acc1;
            *(float4*)&msg[hbase + (size_t)(v0+2)*DD + d0 + tx*4] = acc2;
            *(float4*)&msg[hbase + (size_t)(v0+3)*DD + d0 + tx*4] = acc3;
        }
    }
}

// ---------------- big GEMM: C[M,512] = Am[M,512] @ Bm[512,512] (fp32) ----------------
// tile 128x64, BK=16, 256 threads, 8x4 register tile per thread.

__global__ __launch_bounds__(256) void k_big_gemm(const float* __restrict__ Am,
                                                  const float* __restrict__ Bm,
                                                  float* __restrict__ C) {
    __shared__ float As[16][132];   // k-major (transposed), pad 132
    __shared__ float Bs[16][68];
    int bx = blockIdx.x;
    int m0 = (bx >> 3) * 128;
    int n0 = (bx & 7) * 64;
    int tid = threadIdx.x;
    int arow = tid >> 1, ahalf = tid & 1;
    int bk = tid >> 4, bc = tid & 15;
    int ty = tid >> 4, tx = tid & 15;

    float4 acc[8];
    #pragma unroll
    for (int i = 0; i < 8; ++i) acc[i] = make_float4(0,0,0,0);

    const float* aptr = Am + (size_t)(m0 + arow) * DD + ahalf * 8;
    const float* bptr = Bm + (size_t)bk * DD + n0 + bc * 4;

    for (int k0 = 0; k0 < DD; k0 += 16) {
        float4 la0 = *(const float4*)(aptr + k0);
        float4 la1 = *(const float4*)(aptr + k0 + 4);
        float4 lb  = *(const float4*)(bptr + (size_t)k0 * DD);
        __syncthreads();
        int kb = ahalf * 8;
        As[kb+0][arow] = la0.x; As[kb+1][arow] = la0.y;
        As[kb+2][arow] = la0.z; As[kb+3][arow] = la0.w;
        As[kb+4][arow] = la1.x; As[kb+5][arow] = la1.y;
        As[kb+6][arow] = la1.z; As[kb+7][arow] = la1.w;
        *(float4*)&Bs[bk][bc*4] = lb;
        __syncthreads();
        #pragma unroll
        for (int kk = 0; kk < 16; ++kk) {
            float4 a0 = *(float4*)&As[kk][ty*8];
            float4 a1 = *(float4*)&As[kk][ty*8+4];
            float4 b  = *(float4*)&Bs[kk][tx*4];
#define BACC(I, S) \
    acc[I].x = fmaf(S, b.x, acc[I].x); acc[I].y = fmaf(S, b.y, acc[I].y); \
    acc[I].z = fmaf(S, b.z, acc[I].z); acc[I].w = fmaf(S, b.w, acc[I].w);
            BACC(0, a0.x) BACC(1, a0.y) BACC(2, a0.z) BACC(3, a0.w)
            BACC(4, a1.x) BACC(5, a1.y) BACC(6, a1.z) BACC(7, a1.w)
#undef BACC
        }
    }
    #pragma unroll
    for (int r = 0; r < 8; ++r) {
        *(float4*)&C[(size_t)(m0 + ty*8 + r) * DD + n0 + tx*4] = acc[r];
    }
}

// ---------------- per-graph column stats + batch-sum atomics ----------------

__global__ __launch_bounds__(256) void k_stats(const float* __restrict__ x,
        float* __restrict__ mug, float* __restrict__ rsg,
        float* __restrict__ sumb, float* __restrict__ sumq) {
    int g = blockIdx.x, tid = threadIdx.x;
    size_t base = (size_t)g * NPG * DD;
    float s0 = 0, q0 = 0, s1 = 0, q1 = 0;
    for (int v = 0; v < NPG; ++v) {
        float a = x[base + (size_t)v*DD + tid];
        float b = x[base + (size_t)v*DD + tid + 256];
        s0 += a; q0 = fmaf(a, a, q0);
        s1 += b; q1 = fmaf(b, b, q1);
    }
    const float inv = 1.0f / NPG;
    float m0 = s0 * inv, m1 = s1 * inv;
    mug[(size_t)g*DD + tid]       = m0;
    mug[(size_t)g*DD + tid + 256] = m1;
    rsg[(size_t)g*DD + tid]       = 1.0f / sqrtf(fmaf(-m0, m0, q0*inv) + EPSN);
    rsg[(size_t)g*DD + tid + 256] = 1.0f / sqrtf(fmaf(-m1, m1, q1*inv) + EPSN);
    atomicAdd(&sumb[tid],       s0);
    atomicAdd(&sumq[tid],       q0);
    atomicAdd(&sumb[tid + 256], s1);
    atomicAdd(&sumq[tid + 256], q1);
}

// ---------------- fused norm + leaky + graph-mean readout (in-place) ----------------

__global__ __launch_bounds__(256) void k_norm(float* __restrict__ x,
        const float* __restrict__ mug, const float* __restrict__ rsg,
        const float* __restrict__ sumb, const float* __restrict__ sumq,
        const float* __restrict__ gamma, const float* __restrict__ beta,
        const float* __restrict__ lam, float* __restrict__ out, int l) {
    __shared__ float emb[4][DD];
    int g = blockIdx.x, tid = threadIdx.x;
    int lane = tid & 63, wave = tid >> 6;
    int cb = lane * 8;
    float l0 = lam[0], l1 = lam[1], l2 = lam[2];
    const float invN = 1.0f / NN;

    // fold batch-norm + graph-norm + affine into y = P*x + R*nn + Q (per column)
    float P[8], Q[8], R[8];
    #pragma unroll
    for (int j = 0; j < 8; ++j) {
        int c = cb + j;
        float gm = gamma[c], bt = beta[c];
        float mg = mug[(size_t)g*DD + c], rg = rsg[(size_t)g*DD + c];
        float mb = sumb[c] * invN;
        float rb = 1.0f / sqrtf(fmaf(-mb, mb, sumq[c]*invN) + EPSN);
        P[j] = gm * (l0*rb + l1*rg);
        Q[j] = bt - gm * (l0*mb*rb + l1*mg*rg);
        R[j] = gm * l2;
    }

    float av[8];
    #pragma unroll
    for (int j = 0; j < 8; ++j) av[j] = 0.f;

    size_t base = (size_t)g * NPG * DD;
    for (int v = wave; v < NPG; v += 4) {     // each wave owns full rows -> node stats local
        float* rp = x + base + (size_t)v*DD + cb;
        float4 r0 = *(float4*)rp;
        float4 r1 = *(float4*)(rp + 4);
        float vals[8] = {r0.x, r0.y, r0.z, r0.w, r1.x, r1.y, r1.z, r1.w};
        float s = 0, q = 0;
        #pragma unroll
        for (int j = 0; j < 8; ++j) { s += vals[j]; q = fmaf(vals[j], vals[j], q); }
        #pragma unroll
        for (int off = 1; off < 64; off <<= 1) {
            s += __shfl_xor(s, off, 64);
            q += __shfl_xor(q, off, 64);
        }
        float mn = s * (1.0f/DD);
        float rn = 1.0f / sqrtf(fmaf(-mn, mn, q*(1.0f/DD)) + EPSN);
        float o[8];
        #pragma unroll
        for (int j = 0; j < 8; ++j) {
            float xv = vals[j];
            float nn = (xv - mn) * rn;
            float y = fmaf(P[j], xv, fmaf(R[j], nn, Q[j]));
            y = y > 0.f ? y : SLOPE * y;
            o[j] = y;
            av[j] += y;
        }
        *(float4*)rp       = make_float4(o[0], o[1], o[2], o[3]);
        *(float4*)(rp + 4) = make_float4(o[4], o[5], o[6], o[7]);
    }
    #pragma unroll
    for (int j = 0; j < 8; ++j) emb[wave][cb + j] = av[j];
    __syncthreads();
    for (int c = tid; c < DD; c += 256) {
        float e = (emb[0][c] + emb[1][c] + emb[2][c] + emb[3][c]) * (1.0f/NPG);
        e = e > 0.f ? e : SLOPE * e;               // final leaky on concatenated embedding
        out[(size_t)g * (3*DD) + l*DD + c] = e;
    }
}

// ---------------- host launch ----------------

extern "C" void kernel_launch(void* const* d_in, const int* in_sizes, int n_in,
                              void* d_out, int out_size, void* d_ws, size_t ws_size,
                              hipStream_t stream) {
    const float* nodeF   = (const float*)d_in[0];
    const int*   src     = (const int*)d_in[1];
    const int*   dst     = (const int*)d_in[2];
    // d_in[3] = graph_ids (implied by node index / NPG)
    const float* W       = (const float*)d_in[4];
    const float* gamma   = (const float*)d_in[5];
    const float* beta    = (const float*)d_in[6];
    const float* lambdas = (const float*)d_in[7];
    float* out = (float*)d_out;

    float* ws   = (float*)d_ws;
    float* cOut = ws;                                   // [NN]   (deg accumulator -> rsqrt)
    float* cIn  = cOut + NN;                            // [NN]
    float* Abuf = cIn + NN;                             // [BG*100*100]  41 MB
    float* bufM = Abuf + (size_t)BG*NPG*NPG;            // [NN*DD] msg   210 MB
    float* bufH = bufM + (size_t)NN*DD;                 // [NN*DD] x / h 210 MB
    float* mug  = bufH + (size_t)NN*DD;                 // [BG*DD]
    float* rsg  = mug  + (size_t)BG*DD;                 // [BG*DD]
    float* sumb = rsg  + (size_t)BG*DD;                 // [DD]
    float* sumq = sumb + DD;                            // [DD]

    hipMemsetAsync(cOut, 0, 2*(size_t)NN*sizeof(float), stream);
    hipMemsetAsync(Abuf, 0, (size_t)BG*NPG*NPG*sizeof(float), stream);
    k_degrees<<<EE/256, 256, 0, stream>>>(src, dst, cOut, cIn);
    k_deg_to_c<<<NN/256, 256, 0, stream>>>(cOut, cIn);
    k_build_A<<<EE/256, 256, 0, stream>>>(src, dst, Abuf);
    k_scale_A<<<(BG*NPG*NPG)/256, 256, 0, stream>>>(Abuf, cOut, cIn);

    const float* hcur = nodeF;
    for (int l = 0; l < 3; ++l) {
        k_graph_gemm<<<BG, 256, 0, stream>>>(Abuf, hcur, bufM);
        k_big_gemm<<<(NN/128)*(DD/64), 256, 0, stream>>>(bufM, W + (size_t)l*DD*DD, bufH);
        hipMemsetAsync(sumb, 0, 2*DD*sizeof(float), stream);
        k_stats<<<BG, 256, 0, stream>>>(bufH, mug, rsg, sumb, sumq);
        k_norm<<<BG, 256, 0, stream>>>(bufH, mug, rsg, sumb, sumq,
                                       gamma + l*DD, beta + l*DD, lambdas + l*3, out, l);
        hcur = bufH;
    }
}

// Round 4
// 2364.890 us; speedup vs baseline: 1.3958x; 1.3958x over previous
//
#include <hip/hip_runtime.h>
#include <math.h>

#define NN 102400          // total nodes
#define BG 1024            // graphs
#define NPG 100            // nodes per graph
#define EPG 1600
#define EE (BG*EPG)        // 1,638,400 edges
#define DD 512
#define EPSN 1e-5f
#define SLOPE 0.1f

typedef short bf16x8 __attribute__((ext_vector_type(8)));
typedef float f32x4 __attribute__((ext_vector_type(4)));
typedef __attribute__((address_space(1))) const unsigned int gu32;
typedef __attribute__((address_space(3))) unsigned int lu32;

// split fp32 v into bf16 hi (RNE) + bf16 lo (RNE of residual)
__device__ __forceinline__ void split_bf16(float v, unsigned short& hi, unsigned short& lo) {
    unsigned u = __float_as_uint(v);
    unsigned r = (u + 0x7FFFu + ((u >> 16) & 1u)) >> 16;
    hi = (unsigned short)r;
    float l = v - __uint_as_float(r << 16);
    unsigned ul = __float_as_uint(l);
    unsigned rl = (ul + 0x7FFFu + ((ul >> 16) & 1u)) >> 16;
    lo = (unsigned short)rl;
}

// ---------------- setup kernels ----------------

__global__ __launch_bounds__(256) void k_degrees(const int* __restrict__ src,
                                                 const int* __restrict__ dst,
                                                 float* degOut, float* degIn) {
    int e = blockIdx.x * 256 + threadIdx.x;        // grid is exactly EE/256
    atomicAdd(&degOut[src[e]], 1.0f);
    atomicAdd(&degIn[dst[e]], 1.0f);
}

__global__ __launch_bounds__(256) void k_deg_to_c(float* cOut, float* cIn) {
    int i = blockIdx.x * 256 + threadIdx.x;        // grid exactly NN/256
    float a = cOut[i]; a = a < 1.0f ? 1.0f : a;
    cOut[i] = 1.0f / sqrtf(a);
    float b = cIn[i]; b = b < 1.0f ? 1.0f : b;
    cIn[i] = 1.0f / sqrtf(b);
}

__global__ __launch_bounds__(256) void k_build_A(const int* __restrict__ src,
                                                 const int* __restrict__ dst,
                                                 float* __restrict__ A) {
    int e = blockIdx.x * 256 + threadIdx.x;
    int s = src[e], d = dst[e];
    int g = s / NPG;
    int u = s - g * NPG;
    int v = d - g * NPG;                            // dst in same graph by construction
    atomicAdd(&A[(size_t)g * (NPG*NPG) + v * NPG + u], 1.0f);
}

__global__ __launch_bounds__(256) void k_scale_A(float* __restrict__ A,
                                                 const float* __restrict__ cOut,
                                                 const float* __restrict__ cIn) {
    int idx = blockIdx.x * 256 + threadIdx.x;       // grid exactly BG*10000/256
    int g = idx / (NPG*NPG);
    int r = idx - g * (NPG*NPG);
    int v = r / NPG;
    int u = r - v * NPG;
    A[idx] *= cIn[g*NPG + v] * cOut[g*NPG + u];
}

// W[l] (k-major [512][512] fp32) -> WhiT/WloT ([n][k] bf16 hi/lo), per layer
__global__ __launch_bounds__(256) void k_prepW(const float* __restrict__ W,
        unsigned short* __restrict__ wHiT, unsigned short* __restrict__ wLoT) {
    __shared__ float tile[64][65];
    int b = blockIdx.x;           // 0..191 = 3 layers x 8x8 tiles of 64x64
    int l = b >> 6;
    int r8 = b & 63;
    int ko = (r8 >> 3) * 64, no = (r8 & 7) * 64;
    const float* Wl = W + (size_t)l * DD * DD;
    int t = threadIdx.x;
    #pragma unroll
    for (int i = 0; i < 16; ++i) {
        int idx = i * 256 + t;
        int r = idx >> 6, c = idx & 63;
        tile[r][c] = Wl[(size_t)(ko + r) * DD + no + c];
    }
    __syncthreads();
    size_t obase = (size_t)l * DD * DD;
    #pragma unroll
    for (int i = 0; i < 16; ++i) {
        int idx = i * 256 + t;
        int r = idx >> 6, c = idx & 63;    // r = n-local, c = k-local
        float v = tile[c][r];
        unsigned short hi, lo;
        split_bf16(v, hi, lo);
        wHiT[obase + (size_t)(no + r) * DD + ko + c] = hi;
        wLoT[obase + (size_t)(no + r) * DD + ko + c] = lo;
    }
}

// ---------------- per-graph dense aggregation: msg = A' @ h ----------------
// one block per graph; A' (100x100) cached in LDS; outputs bf16 hi/lo split.

#define GG_DC 32

__global__ __launch_bounds__(256) void k_graph_gemm(const float* __restrict__ A,
                                                    const float* __restrict__ h,
                                                    unsigned short* __restrict__ msgHi,
                                                    unsigned short* __restrict__ msgLo) {
    __shared__ float As[NPG][108];
    __shared__ float hs[NPG][GG_DC];
    int g = blockIdx.x, tid = threadIdx.x;
    const float* Ag = A + (size_t)g * (NPG*NPG);
    size_t hbase = (size_t)g * NPG * DD;

    for (int i = tid; i < NPG*NPG; i += 256) {
        int v = i / NPG;
        As[v][i - v*NPG] = Ag[i];
    }

    int tx = tid & 7;           // d-quad within 32-col chunk
    int ty = tid >> 3;          // v-quad index: v0 = 4*ty (ty<=24 active)
    int v0 = ty * 4;

    for (int d0 = 0; d0 < DD; d0 += GG_DC) {
        int i0 = tid, i1 = tid + 256, i2 = tid + 512, i3 = tid + 768;
        float4 t0, t1, t2, t3;
        t0 = *(const float4*)&h[hbase + (size_t)(i0 >> 3) * DD + d0 + (i0 & 7) * 4];
        t1 = *(const float4*)&h[hbase + (size_t)(i1 >> 3) * DD + d0 + (i1 & 7) * 4];
        t2 = *(const float4*)&h[hbase + (size_t)(i2 >> 3) * DD + d0 + (i2 & 7) * 4];
        if (tid < 32)
            t3 = *(const float4*)&h[hbase + (size_t)(i3 >> 3) * DD + d0 + (i3 & 7) * 4];
        __syncthreads();
        *(float4*)&hs[i0 >> 3][(i0 & 7) * 4] = t0;
        *(float4*)&hs[i1 >> 3][(i1 & 7) * 4] = t1;
        *(float4*)&hs[i2 >> 3][(i2 & 7) * 4] = t2;
        if (tid < 32) *(float4*)&hs[i3 >> 3][(i3 & 7) * 4] = t3;
        __syncthreads();

        if (v0 < NPG) {
            float4 acc0 = make_float4(0,0,0,0);
            float4 acc1 = acc0, acc2 = acc0, acc3 = acc0;
            for (int u0 = 0; u0 < NPG; u0 += 4) {   // 25 iterations
                float4 a0 = *(float4*)&As[v0+0][u0];
                float4 a1 = *(float4*)&As[v0+1][u0];
                float4 a2 = *(float4*)&As[v0+2][u0];
                float4 a3 = *(float4*)&As[v0+3][u0];
                float4 h0 = *(float4*)&hs[u0+0][tx*4];
                float4 h1 = *(float4*)&hs[u0+1][tx*4];
                float4 h2 = *(float4*)&hs[u0+2][tx*4];
                float4 h3 = *(float4*)&hs[u0+3][tx*4];
#define GACC(ACC, AV) \
    ACC.x = fmaf(AV.x, h0.x, fmaf(AV.y, h1.x, fmaf(AV.z, h2.x, fmaf(AV.w, h3.x, ACC.x)))); \
    ACC.y = fmaf(AV.x, h0.y, fmaf(AV.y, h1.y, fmaf(AV.z, h2.y, fmaf(AV.w, h3.y, ACC.y)))); \
    ACC.z = fmaf(AV.x, h0.z, fmaf(AV.y, h1.z, fmaf(AV.z, h2.z, fmaf(AV.w, h3.z, ACC.z)))); \
    ACC.w = fmaf(AV.x, h0.w, fmaf(AV.y, h1.w, fmaf(AV.z, h2.w, fmaf(AV.w, h3.w, ACC.w))));
                GACC(acc0, a0) GACC(acc1, a1) GACC(acc2, a2) GACC(acc3, a3)
#undef GACC
            }
#define STORE_HL(ACC, ROW) { \
            ushort4 h4, l4; \
            split_bf16(ACC.x, h4.x, l4.x); split_bf16(ACC.y, h4.y, l4.y); \
            split_bf16(ACC.z, h4.z, l4.z); split_bf16(ACC.w, h4.w, l4.w); \
            *(ushort4*)&msgHi[hbase + (size_t)(ROW)*DD + d0 + tx*4] = h4; \
            *(ushort4*)&msgLo[hbase + (size_t)(ROW)*DD + d0 + tx*4] = l4; }
            STORE_HL(acc0, v0+0) STORE_HL(acc1, v0+1)
            STORE_HL(acc2, v0+2) STORE_HL(acc3, v0+3)
#undef STORE_HL
        }
    }
}

// ---------------- big GEMM via MFMA bf16x3: C[M,512] = msg[M,512] @ W[512,512] ----------------
// m97 structure: 128x128 tile, 4 waves (2x2 of 64x64), BK=32, global_load_lds(16B),
// K_eff = 3*512 (parts: hi*hi, lo*hi, hi*lo), fp32 accumulate.

__global__ __launch_bounds__(256) void k_mfma_gemm(
        const unsigned short* __restrict__ aHi, const unsigned short* __restrict__ aLo,
        const unsigned short* __restrict__ bHiT, const unsigned short* __restrict__ bLoT,
        float* __restrict__ C) {
    __shared__ unsigned short lds[8192];  // A: [0,4096) = [128][32], B: [4096,8192) = [128][32]
    int bx = blockIdx.x;
    int m0 = (bx >> 2) << 7;        // n-fast: 4 consecutive blocks share the A panel
    int n0 = (bx & 3) << 7;
    int tid = threadIdx.x;
    int wid = tid >> 6, lane = tid & 63;
    int wr = wid >> 1, wc = wid & 1;
    int lr = lane & 15, lk = (lane >> 4) * 8;

    f32x4 zero = {0.f, 0.f, 0.f, 0.f};
    f32x4 acc[4][4];
    #pragma unroll
    for (int i = 0; i < 4; ++i)
        #pragma unroll
        for (int j = 0; j < 4; ++j) acc[i][j] = zero;

    // staging: chunk c covers LDS bytes [c*16, c*16+16); c = instr*256 + tid
    int rA0 = tid >> 2,           kq0 = (tid & 3) * 8;
    int rA1 = (tid + 256) >> 2,   kq1 = (tid & 3) * 8;   // (c1&3)==(tid&3)
    unsigned short* lA0 = lds + wid * 512;               // wave-uniform LDS bases
    unsigned short* lA1 = lds + 2048 + wid * 512;
    unsigned short* lB0 = lds + 4096 + wid * 512;
    unsigned short* lB1 = lds + 6144 + wid * 512;

    for (int kt = 0; kt < 48; ++kt) {
        int part = kt >> 4;                     // 16 k-tiles per 512-wide part
        const unsigned short* pA = (part == 1) ? aLo : aHi;    // hi, lo, hi
        const unsigned short* pB = (part == 2) ? bLoT : bHiT;  // hi, hi, lo
        int kl = (kt & 15) << 5;
        __syncthreads();   // all waves done reading previous tile
        __builtin_amdgcn_global_load_lds((gu32*)(pA + (size_t)(m0 + rA0) * DD + kl + kq0),
                                         (lu32*)lA0, 16, 0, 0);
        __builtin_amdgcn_global_load_lds((gu32*)(pA + (size_t)(m0 + rA1) * DD + kl + kq1),
                                         (lu32*)lA1, 16, 0, 0);
        __builtin_amdgcn_global_load_lds((gu32*)(pB + (size_t)(n0 + rA0) * DD + kl + kq0),
                                         (lu32*)lB0, 16, 0, 0);
        __builtin_amdgcn_global_load_lds((gu32*)(pB + (size_t)(n0 + rA1) * DD + kl + kq1),
                                         (lu32*)lB1, 16, 0, 0);
        __syncthreads();   // vmcnt(0) drained by barrier -> tile visible

        bf16x8 af[4], bfr[4];
        #pragma unroll
        for (int i = 0; i < 4; ++i) {
            af[i]  = *(const bf16x8*)(lds + (wr*64 + i*16 + lr) * 32 + lk);
            bfr[i] = *(const bf16x8*)(lds + 4096 + (wc*64 + i*16 + lr) * 32 + lk);
        }
        #pragma unroll
        for (int mi = 0; mi < 4; ++mi)
            #pragma unroll
            for (int ni = 0; ni < 4; ++ni)
                acc[mi][ni] = __builtin_amdgcn_mfma_f32_16x16x32_bf16(
                                  af[mi], bfr[ni], acc[mi][ni], 0, 0, 0);
    }

    #pragma unroll
    for (int mi = 0; mi < 4; ++mi) {
        int row0 = wr*64 + mi*16 + (lane >> 4) * 4;
        #pragma unroll
        for (int j = 0; j < 4; ++j) {
            int row = m0 + row0 + j;
            int col = n0 + wc*64 + lr;
            #pragma unroll
            for (int ni = 0; ni < 4; ++ni)
                C[(size_t)row * DD + col + ni*16] = acc[mi][ni][j];
        }
    }
}

// ---------------- per-graph column stats + batch-sum atomics ----------------

__global__ __launch_bounds__(256) void k_stats(const float* __restrict__ x,
        float* __restrict__ mug, float* __restrict__ rsg,
        float* __restrict__ sumb, float* __restrict__ sumq) {
    int g = blockIdx.x, tid = threadIdx.x;
    size_t base = (size_t)g * NPG * DD;
    float s0 = 0, q0 = 0, s1 = 0, q1 = 0;
    for (int v = 0; v < NPG; ++v) {
        float a = x[base + (size_t)v*DD + tid];
        float b = x[base + (size_t)v*DD + tid + 256];
        s0 += a; q0 = fmaf(a, a, q0);
        s1 += b; q1 = fmaf(b, b, q1);
    }
    const float inv = 1.0f / NPG;
    float m0 = s0 * inv, m1 = s1 * inv;
    mug[(size_t)g*DD + tid]       = m0;
    mug[(size_t)g*DD + tid + 256] = m1;
    rsg[(size_t)g*DD + tid]       = 1.0f / sqrtf(fmaf(-m0, m0, q0*inv) + EPSN);
    rsg[(size_t)g*DD + tid + 256] = 1.0f / sqrtf(fmaf(-m1, m1, q1*inv) + EPSN);
    atomicAdd(&sumb[tid],       s0);
    atomicAdd(&sumq[tid],       q0);
    atomicAdd(&sumb[tid + 256], s1);
    atomicAdd(&sumq[tid + 256], q1);
}

// ---------------- fused norm + leaky + graph-mean readout (in-place) ----------------

__global__ __launch_bounds__(256) void k_norm(float* __restrict__ x,
        const float* __restrict__ mug, const float* __restrict__ rsg,
        const float* __restrict__ sumb, const float* __restrict__ sumq,
        const float* __restrict__ gamma, const float* __restrict__ beta,
        const float* __restrict__ lam, float* __restrict__ out, int l) {
    __shared__ float emb[4][DD];
    int g = blockIdx.x, tid = threadIdx.x;
    int lane = tid & 63, wave = tid >> 6;
    int cb = lane * 8;
    float l0 = lam[0], l1 = lam[1], l2 = lam[2];
    const float invN = 1.0f / NN;

    // fold batch-norm + graph-norm + affine into y = P*x + R*nn + Q (per column)
    float P[8], Q[8], R[8];
    #pragma unroll
    for (int j = 0; j < 8; ++j) {
        int c = cb + j;
        float gm = gamma[c], bt = beta[c];
        float mg = mug[(size_t)g*DD + c], rg = rsg[(size_t)g*DD + c];
        float mb = sumb[c] * invN;
        float rb = 1.0f / sqrtf(fmaf(-mb, mb, sumq[c]*invN) + EPSN);
        P[j] = gm * (l0*rb + l1*rg);
        Q[j] = bt - gm * (l0*mb*rb + l1*mg*rg);
        R[j] = gm * l2;
    }

    float av[8];
    #pragma unroll
    for (int j = 0; j < 8; ++j) av[j] = 0.f;

    size_t base = (size_t)g * NPG * DD;
    for (int v = wave; v < NPG; v += 4) {     // each wave owns full rows -> node stats local
        float* rp = x + base + (size_t)v*DD + cb;
        float4 r0 = *(float4*)rp;
        float4 r1 = *(float4*)(rp + 4);
        float vals[8] = {r0.x, r0.y, r0.z, r0.w, r1.x, r1.y, r1.z, r1.w};
        float s = 0, q = 0;
        #pragma unroll
        for (int j = 0; j < 8; ++j) { s += vals[j]; q = fmaf(vals[j], vals[j], q); }
        #pragma unroll
        for (int off = 1; off < 64; off <<= 1) {
            s += __shfl_xor(s, off, 64);
            q += __shfl_xor(q, off, 64);
        }
        float mn = s * (1.0f/DD);
        float rn = 1.0f / sqrtf(fmaf(-mn, mn, q*(1.0f/DD)) + EPSN);
        float o[8];
        #pragma unroll
        for (int j = 0; j < 8; ++j) {
            float xv = vals[j];
            float nn = (xv - mn) * rn;
            float y = fmaf(P[j], xv, fmaf(R[j], nn, Q[j]));
            y = y > 0.f ? y : SLOPE * y;
            o[j] = y;
            av[j] += y;
        }
        *(float4*)rp       = make_float4(o[0], o[1], o[2], o[3]);
        *(float4*)(rp + 4) = make_float4(o[4], o[5], o[6], o[7]);
    }
    #pragma unroll
    for (int j = 0; j < 8; ++j) emb[wave][cb + j] = av[j];
    __syncthreads();
    for (int c = tid; c < DD; c += 256) {
        float e = (emb[0][c] + emb[1][c] + emb[2][c] + emb[3][c]) * (1.0f/NPG);
        e = e > 0.f ? e : SLOPE * e;               // final leaky on concatenated embedding
        out[(size_t)g * (3*DD) + l*DD + c] = e;
    }
}

// ---------------- host launch ----------------

extern "C" void kernel_launch(void* const* d_in, const int* in_sizes, int n_in,
                              void* d_out, int out_size, void* d_ws, size_t ws_size,
                              hipStream_t stream) {
    const float* nodeF   = (const float*)d_in[0];
    const int*   src     = (const int*)d_in[1];
    const int*   dst     = (const int*)d_in[2];
    // d_in[3] = graph_ids (implied by node index / NPG)
    const float* W       = (const float*)d_in[4];
    const float* gamma   = (const float*)d_in[5];
    const float* beta    = (const float*)d_in[6];
    const float* lambdas = (const float*)d_in[7];
    float* out = (float*)d_out;

    float* ws   = (float*)d_ws;
    float* cOut = ws;                                   // [NN]
    float* cIn  = cOut + NN;                            // [NN]
    float* Abuf = cIn + NN;                             // [BG*100*100]  41 MB
    float* bufH = Abuf + (size_t)BG*NPG*NPG;            // [NN*DD] fp32  210 MB
    float* mug  = bufH + (size_t)NN*DD;                 // [BG*DD]
    float* rsg  = mug  + (size_t)BG*DD;                 // [BG*DD]
    float* sumb = rsg  + (size_t)BG*DD;                 // [DD]
    float* sumq = sumb + DD;                            // [DD]
    unsigned short* msgHi = (unsigned short*)(sumq + DD);            // [NN*DD] bf16  105 MB
    unsigned short* msgLo = msgHi + (size_t)NN*DD;                   // [NN*DD] bf16  105 MB
    unsigned short* wHiT  = msgLo + (size_t)NN*DD;                   // [3*DD*DD]
    unsigned short* wLoT  = wHiT  + (size_t)3*DD*DD;                 // [3*DD*DD]

    hipMemsetAsync(cOut, 0, 2*(size_t)NN*sizeof(float), stream);
    hipMemsetAsync(Abuf, 0, (size_t)BG*NPG*NPG*sizeof(float), stream);
    k_degrees<<<EE/256, 256, 0, stream>>>(src, dst, cOut, cIn);
    k_deg_to_c<<<NN/256, 256, 0, stream>>>(cOut, cIn);
    k_build_A<<<EE/256, 256, 0, stream>>>(src, dst, Abuf);
    k_scale_A<<<(BG*NPG*NPG)/256, 256, 0, stream>>>(Abuf, cOut, cIn);
    k_prepW<<<192, 256, 0, stream>>>(W, wHiT, wLoT);

    const float* hcur = nodeF;
    for (int l = 0; l < 3; ++l) {
        k_graph_gemm<<<BG, 256, 0, stream>>>(Abuf, hcur, msgHi, msgLo);
        k_mfma_gemm<<<(NN/128)*(DD/128), 256, 0, stream>>>(
            msgHi, msgLo, wHiT + (size_t)l*DD*DD, wLoT + (size_t)l*DD*DD, bufH);
        hipMemsetAsync(sumb, 0, 2*DD*sizeof(float), stream);
        k_stats<<<BG, 256, 0, stream>>>(bufH, mug, rsg, sumb, sumq);
        k_norm<<<BG, 256, 0, stream>>>(bufH, mug, rsg, sumb, sumq,
                                       gamma + l*DD, beta + l*DD, lambdas + l*3, out, l);
        hcur = bufH;
    }
}

// Round 6
// 2005.582 us; speedup vs baseline: 1.6458x; 1.1792x over previous
//
#include <hip/hip_runtime.h>
#include <math.h>

#define NN 102400          // total nodes
#define BG 1024            // graphs
#define NPG 100            // nodes per graph
#define EPG 1600
#define EE (BG*EPG)        // 1,638,400 edges
#define DD 512
#define EPSN 1e-5f
#define SLOPE 0.1f

typedef short bf16x8 __attribute__((ext_vector_type(8)));
typedef float f32x4 __attribute__((ext_vector_type(4)));
typedef __attribute__((address_space(1))) const unsigned int gu32;
typedef __attribute__((address_space(3))) unsigned int lu32;

// split fp32 v into bf16 hi (RNE) + bf16 lo (RNE of residual)
__device__ __forceinline__ void split_bf16(float v, unsigned short& hi, unsigned short& lo) {
    unsigned u = __float_as_uint(v);
    unsigned r = (u + 0x7FFFu + ((u >> 16) & 1u)) >> 16;
    hi = (unsigned short)r;
    float l = v - __uint_as_float(r << 16);
    unsigned ul = __float_as_uint(l);
    unsigned rl = (ul + 0x7FFFu + ((ul >> 16) & 1u)) >> 16;
    lo = (unsigned short)rl;
}

// ---------------- setup kernels ----------------

__global__ __launch_bounds__(256) void k_degrees(const int* __restrict__ src,
                                                 const int* __restrict__ dst,
                                                 float* degOut, float* degIn) {
    int e = blockIdx.x * 256 + threadIdx.x;        // grid is exactly EE/256
    atomicAdd(&degOut[src[e]], 1.0f);
    atomicAdd(&degIn[dst[e]], 1.0f);
}

__global__ __launch_bounds__(256) void k_deg_to_c(float* cOut, float* cIn) {
    int i = blockIdx.x * 256 + threadIdx.x;        // grid exactly NN/256
    float a = cOut[i]; a = a < 1.0f ? 1.0f : a;
    cOut[i] = 1.0f / sqrtf(a);
    float b = cIn[i]; b = b < 1.0f ? 1.0f : b;
    cIn[i] = 1.0f / sqrtf(b);
}

__global__ __launch_bounds__(256) void k_build_A(const int* __restrict__ src,
                                                 const int* __restrict__ dst,
                                                 float* __restrict__ A) {
    int e = blockIdx.x * 256 + threadIdx.x;
    int s = src[e], d = dst[e];
    int g = s / NPG;
    int u = s - g * NPG;
    int v = d - g * NPG;                            // dst in same graph by construction
    atomicAdd(&A[(size_t)g * (NPG*NPG) + v * NPG + u], 1.0f);
}

__global__ __launch_bounds__(256) void k_scale_A(float* __restrict__ A,
                                                 const float* __restrict__ cOut,
                                                 const float* __restrict__ cIn) {
    int idx = blockIdx.x * 256 + threadIdx.x;       // grid exactly BG*10000/256
    int g = idx / (NPG*NPG);
    int r = idx - g * (NPG*NPG);
    int v = r / NPG;
    int u = r - v * NPG;
    A[idx] *= cIn[g*NPG + v] * cOut[g*NPG + u];
}

// W[l] (k-major [512][512] fp32) -> WhiT/WloT ([n][k] bf16 hi/lo), per layer
__global__ __launch_bounds__(256) void k_prepW(const float* __restrict__ W,
        unsigned short* __restrict__ wHiT, unsigned short* __restrict__ wLoT) {
    __shared__ float tile[64][65];
    int b = blockIdx.x;           // 0..191 = 3 layers x 8x8 tiles of 64x64
    int l = b >> 6;
    int r8 = b & 63;
    int ko = (r8 >> 3) * 64, no = (r8 & 7) * 64;
    const float* Wl = W + (size_t)l * DD * DD;
    int t = threadIdx.x;
    #pragma unroll
    for (int i = 0; i < 16; ++i) {
        int idx = i * 256 + t;
        int r = idx >> 6, c = idx & 63;
        tile[r][c] = Wl[(size_t)(ko + r) * DD + no + c];
    }
    __syncthreads();
    size_t obase = (size_t)l * DD * DD;
    #pragma unroll
    for (int i = 0; i < 16; ++i) {
        int idx = i * 256 + t;
        int r = idx >> 6, c = idx & 63;    // r = n-local, c = k-local
        float v = tile[c][r];
        unsigned short hi, lo;
        split_bf16(v, hi, lo);
        wHiT[obase + (size_t)(no + r) * DD + ko + c] = hi;
        wLoT[obase + (size_t)(no + r) * DD + ko + c] = lo;
    }
}

// ---------------- per-graph dense aggregation: msg = A' @ h ----------------
// one block per graph; A' (100x100) cached in LDS; outputs bf16 hi/lo split.

#define GG_DC 32

__global__ __launch_bounds__(256) void k_graph_gemm(const float* __restrict__ A,
                                                    const float* __restrict__ h,
                                                    unsigned short* __restrict__ msgHi,
                                                    unsigned short* __restrict__ msgLo) {
    __shared__ float As[NPG][108];
    __shared__ float hs[NPG][GG_DC];
    int g = blockIdx.x, tid = threadIdx.x;
    const float* Ag = A + (size_t)g * (NPG*NPG);
    size_t hbase = (size_t)g * NPG * DD;

    for (int i = tid; i < NPG*NPG; i += 256) {
        int v = i / NPG;
        As[v][i - v*NPG] = Ag[i];
    }

    int tx = tid & 7;           // d-quad within 32-col chunk
    int ty = tid >> 3;          // v-quad index: v0 = 4*ty (ty<=24 active)
    int v0 = ty * 4;

    for (int d0 = 0; d0 < DD; d0 += GG_DC) {
        int i0 = tid, i1 = tid + 256, i2 = tid + 512, i3 = tid + 768;
        float4 t0, t1, t2, t3;
        t0 = *(const float4*)&h[hbase + (size_t)(i0 >> 3) * DD + d0 + (i0 & 7) * 4];
        t1 = *(const float4*)&h[hbase + (size_t)(i1 >> 3) * DD + d0 + (i1 & 7) * 4];
        t2 = *(const float4*)&h[hbase + (size_t)(i2 >> 3) * DD + d0 + (i2 & 7) * 4];
        if (tid < 32)
            t3 = *(const float4*)&h[hbase + (size_t)(i3 >> 3) * DD + d0 + (i3 & 7) * 4];
        __syncthreads();
        *(float4*)&hs[i0 >> 3][(i0 & 7) * 4] = t0;
        *(float4*)&hs[i1 >> 3][(i1 & 7) * 4] = t1;
        *(float4*)&hs[i2 >> 3][(i2 & 7) * 4] = t2;
        if (tid < 32) *(float4*)&hs[i3 >> 3][(i3 & 7) * 4] = t3;
        __syncthreads();

        if (v0 < NPG) {
            float4 acc0 = make_float4(0,0,0,0);
            float4 acc1 = acc0, acc2 = acc0, acc3 = acc0;
            for (int u0 = 0; u0 < NPG; u0 += 4) {   // 25 iterations
                float4 a0 = *(float4*)&As[v0+0][u0];
                float4 a1 = *(float4*)&As[v0+1][u0];
                float4 a2 = *(float4*)&As[v0+2][u0];
                float4 a3 = *(float4*)&As[v0+3][u0];
                float4 h0 = *(float4*)&hs[u0+0][tx*4];
                float4 h1 = *(float4*)&hs[u0+1][tx*4];
                float4 h2 = *(float4*)&hs[u0+2][tx*4];
                float4 h3 = *(float4*)&hs[u0+3][tx*4];
#define GACC(ACC, AV) \
    ACC.x = fmaf(AV.x, h0.x, fmaf(AV.y, h1.x, fmaf(AV.z, h2.x, fmaf(AV.w, h3.x, ACC.x)))); \
    ACC.y = fmaf(AV.x, h0.y, fmaf(AV.y, h1.y, fmaf(AV.z, h2.y, fmaf(AV.w, h3.y, ACC.y)))); \
    ACC.z = fmaf(AV.x, h0.z, fmaf(AV.y, h1.z, fmaf(AV.z, h2.z, fmaf(AV.w, h3.z, ACC.z)))); \
    ACC.w = fmaf(AV.x, h0.w, fmaf(AV.y, h1.w, fmaf(AV.z, h2.w, fmaf(AV.w, h3.w, ACC.w))));
                GACC(acc0, a0) GACC(acc1, a1) GACC(acc2, a2) GACC(acc3, a3)
#undef GACC
            }
#define STORE_HL(ACC, ROW) { \
            ushort4 h4, l4; \
            split_bf16(ACC.x, h4.x, l4.x); split_bf16(ACC.y, h4.y, l4.y); \
            split_bf16(ACC.z, h4.z, l4.z); split_bf16(ACC.w, h4.w, l4.w); \
            *(ushort4*)&msgHi[hbase + (size_t)(ROW)*DD + d0 + tx*4] = h4; \
            *(ushort4*)&msgLo[hbase + (size_t)(ROW)*DD + d0 + tx*4] = l4; }
            STORE_HL(acc0, v0+0) STORE_HL(acc1, v0+1)
            STORE_HL(acc2, v0+2) STORE_HL(acc3, v0+3)
#undef STORE_HL
        }
    }
}

// ---------------- big GEMM via MFMA bf16x3: C[M,512] = msg[M,512] @ W[512,512] ----------------
// 128x128 tile, 4 waves, BK=32, global_load_lds(16B), double-buffered 2-phase prefetch,
// XCD-chunked block swizzle, conflict-free LDS granule permutation:
//   granule (r,c) [r=row 0..127, c=16B-quad 0..3] stored at slot (rho(r), c^(r&3)),
//   rho(r)=r^((r>>2)&1) (self-inverse). gload_lds dest stays LINEAR; the global
//   SOURCE per slot is permuted (m173 pattern), reads apply the forward map.

__global__ __launch_bounds__(256, 4) void k_mfma_gemm(
        const unsigned short* __restrict__ aHi, const unsigned short* __restrict__ aLo,
        const unsigned short* __restrict__ bHiT, const unsigned short* __restrict__ bLoT,
        float* __restrict__ C) {
    __shared__ unsigned short lds[16384];  // 32KB: buf q at q*8192 (A), q*8192+4096 (B)
    int bphys = blockIdx.x;
    // XCD swizzle: 3200 blocks, 8 XCDs, 400/XCD; 4 consecutive logicals share an A panel
    int bx = (bphys & 7) * 400 + (bphys >> 3);
    int m0 = (bx >> 2) << 7;
    int n0 = (bx & 3) << 7;
    int tid = threadIdx.x;
    int wid = tid >> 6, lane = tid & 63;
    int wr = wid >> 1, wc = wid & 1;
    int lr = lane & 15;

    f32x4 zero = {0.f, 0.f, 0.f, 0.f};
    f32x4 acc[4][4];
    #pragma unroll
    for (int i = 0; i < 4; ++i)
        #pragma unroll
        for (int j = 0; j < 4; ++j) acc[i][j] = zero;

    // ---- staging source coords: slot s -> global granule (r,c) (inverse map) ----
    int s0 = tid,        sr0 = s0 >> 2;
    int s1 = tid + 256,  sr1 = s1 >> 2;
    int r0 = sr0 ^ ((sr0 >> 2) & 1);  int c0 = (s0 & 3) ^ (r0 & 3);
    int r1 = sr1 ^ ((sr1 >> 2) & 1);  int c1 = (s1 & 3) ^ (r1 & 3);
    size_t gA0 = (size_t)(m0 + r0) * DD + c0 * 8;
    size_t gA1 = (size_t)(m0 + r1) * DD + c1 * 8;
    size_t gB0 = (size_t)(n0 + r0) * DD + c0 * 8;
    size_t gB1 = (size_t)(n0 + r1) * DD + c1 * 8;

    // ---- read offsets (shorts, loop-invariant): granule (r,c) at slot (rho(r), c^(r&3)) ----
    int aoff[4], boff[4];
    int cq = lane >> 4;                       // 16B-quad index = k-quad
    #pragma unroll
    for (int i = 0; i < 4; ++i) {
        int ra = wr*64 + i*16 + lr;
        aoff[i] = (ra ^ ((ra >> 2) & 1)) * 32 + ((cq ^ (ra & 3)) * 8);
        int rb = wc*64 + i*16 + lr;
        boff[i] = 4096 + (rb ^ ((rb >> 2) & 1)) * 32 + ((cq ^ (rb & 3)) * 8);
    }

#define STAGE(q, kt_) { \
    int part_ = (kt_) >> 4; \
    const unsigned short* pA_ = (part_ == 1) ? aLo : aHi;    /* hi, lo, hi */ \
    const unsigned short* pB_ = (part_ == 2) ? bLoT : bHiT;  /* hi, hi, lo */ \
    int kl_ = ((kt_) & 15) << 5; \
    unsigned short* base_ = lds + (q) * 8192; \
    __builtin_amdgcn_global_load_lds((gu32*)(pA_ + gA0 + kl_), (lu32*)(base_ + wid*512),        16, 0, 0); \
    __builtin_amdgcn_global_load_lds((gu32*)(pA_ + gA1 + kl_), (lu32*)(base_ + 2048 + wid*512), 16, 0, 0); \
    __builtin_amdgcn_global_load_lds((gu32*)(pB_ + gB0 + kl_), (lu32*)(base_ + 4096 + wid*512), 16, 0, 0); \
    __builtin_amdgcn_global_load_lds((gu32*)(pB_ + gB1 + kl_), (lu32*)(base_ + 6144 + wid*512), 16, 0, 0); \
}

    STAGE(0, 0);
    __syncthreads();          // drains vmcnt(0) -> buf0 ready
    int cur = 0;
    for (int kt = 0; kt < 48; ++kt) {
        if (kt < 47) STAGE(cur ^ 1, kt + 1);    // prefetch next tile (latency hides under compute)
        const unsigned short* bufp = lds + cur * 8192;
        bf16x8 af[4], bfr[4];
        #pragma unroll
        for (int i = 0; i < 4; ++i) {
            af[i]  = *(const bf16x8*)(bufp + aoff[i]);
            bfr[i] = *(const bf16x8*)(bufp + boff[i]);
        }
        #pragma unroll
        for (int mi = 0; mi < 4; ++mi)
            #pragma unroll
            for (int ni = 0; ni < 4; ++ni)
                acc[mi][ni] = __builtin_amdgcn_mfma_f32_16x16x32_bf16(
                                  af[mi], bfr[ni], acc[mi][ni], 0, 0, 0);
        __syncthreads();      // drains prefetch + protects buffer swap
        cur ^= 1;
    }
#undef STAGE

    #pragma unroll
    for (int mi = 0; mi < 4; ++mi) {
        int row0 = wr*64 + mi*16 + (lane >> 4) * 4;
        #pragma unroll
        for (int j = 0; j < 4; ++j) {
            int row = m0 + row0 + j;
            int col = n0 + wc*64 + lr;
            #pragma unroll
            for (int ni = 0; ni < 4; ++ni)
                C[(size_t)row * DD + col + ni*16] = acc[mi][ni][j];
        }
    }
}

// ---------------- per-graph column stats + batch-sum atomics ----------------

__global__ __launch_bounds__(256) void k_stats(const float* __restrict__ x,
        float* __restrict__ mug, float* __restrict__ rsg,
        float* __restrict__ sumb, float* __restrict__ sumq) {
    int g = blockIdx.x, tid = threadIdx.x;
    size_t base = (size_t)g * NPG * DD;
    float s0 = 0, q0 = 0, s1 = 0, q1 = 0;
    for (int v = 0; v < NPG; ++v) {
        float a = x[base + (size_t)v*DD + tid];
        float b = x[base + (size_t)v*DD + tid + 256];
        s0 += a; q0 = fmaf(a, a, q0);
        s1 += b; q1 = fmaf(b, b, q1);
    }
    const float inv = 1.0f / NPG;
    float m0 = s0 * inv, m1 = s1 * inv;
    mug[(size_t)g*DD + tid]       = m0;
    mug[(size_t)g*DD + tid + 256] = m1;
    rsg[(size_t)g*DD + tid]       = 1.0f / sqrtf(fmaf(-m0, m0, q0*inv) + EPSN);
    rsg[(size_t)g*DD + tid + 256] = 1.0f / sqrtf(fmaf(-m1, m1, q1*inv) + EPSN);
    atomicAdd(&sumb[tid],       s0);
    atomicAdd(&sumq[tid],       q0);
    atomicAdd(&sumb[tid + 256], s1);
    atomicAdd(&sumq[tid + 256], q1);
}

// ---------------- fused norm + leaky + graph-mean readout (in-place) ----------------

__global__ __launch_bounds__(256) void k_norm(float* __restrict__ x,
        const float* __restrict__ mug, const float* __restrict__ rsg,
        const float* __restrict__ sumb, const float* __restrict__ sumq,
        const float* __restrict__ gamma, const float* __restrict__ beta,
        const float* __restrict__ lam, float* __restrict__ out, int l) {
    __shared__ float emb[4][DD];
    int g = blockIdx.x, tid = threadIdx.x;
    int lane = tid & 63, wave = tid >> 6;
    int cb = lane * 8;
    float l0 = lam[0], l1 = lam[1], l2 = lam[2];
    const float invN = 1.0f / NN;

    // fold batch-norm + graph-norm + affine into y = P*x + R*nn + Q (per column)
    float P[8], Q[8], R[8];
    #pragma unroll
    for (int j = 0; j < 8; ++j) {
        int c = cb + j;
        float gm = gamma[c], bt = beta[c];
        float mg = mug[(size_t)g*DD + c], rg = rsg[(size_t)g*DD + c];
        float mb = sumb[c] * invN;
        float rb = 1.0f / sqrtf(fmaf(-mb, mb, sumq[c]*invN) + EPSN);
        P[j] = gm * (l0*rb + l1*rg);
        Q[j] = bt - gm * (l0*mb*rb + l1*mg*rg);
        R[j] = gm * l2;
    }

    float av[8];
    #pragma unroll
    for (int j = 0; j < 8; ++j) av[j] = 0.f;

    size_t base = (size_t)g * NPG * DD;
    for (int v = wave; v < NPG; v += 4) {     // each wave owns full rows -> node stats local
        float* rp = x + base + (size_t)v*DD + cb;
        float4 r0 = *(float4*)rp;
        float4 r1 = *(float4*)(rp + 4);
        float vals[8] = {r0.x, r0.y, r0.z, r0.w, r1.x, r1.y, r1.z, r1.w};
        float s = 0, q = 0;
        #pragma unroll
        for (int j = 0; j < 8; ++j) { s += vals[j]; q = fmaf(vals[j], vals[j], q); }
        #pragma unroll
        for (int off = 1; off < 64; off <<= 1) {
            s += __shfl_xor(s, off, 64);
            q += __shfl_xor(q, off, 64);
        }
        float mn = s * (1.0f/DD);
        float rn = 1.0f / sqrtf(fmaf(-mn, mn, q*(1.0f/DD)) + EPSN);
        float o[8];
        #pragma unroll
        for (int j = 0; j < 8; ++j) {
            float xv = vals[j];
            float nn = (xv - mn) * rn;
            float y = fmaf(P[j], xv, fmaf(R[j], nn, Q[j]));
            y = y > 0.f ? y : SLOPE * y;
            o[j] = y;
            av[j] += y;
        }
        *(float4*)rp       = make_float4(o[0], o[1], o[2], o[3]);
        *(float4*)(rp + 4) = make_float4(o[4], o[5], o[6], o[7]);
    }
    #pragma unroll
    for (int j = 0; j < 8; ++j) emb[wave][cb + j] = av[j];
    __syncthreads();
    for (int c = tid; c < DD; c += 256) {
        float e = (emb[0][c] + emb[1][c] + emb[2][c] + emb[3][c]) * (1.0f/NPG);
        e = e > 0.f ? e : SLOPE * e;               // final leaky on concatenated embedding
        out[(size_t)g * (3*DD) + l*DD + c] = e;
    }
}

// ---------------- host launch ----------------

extern "C" void kernel_launch(void* const* d_in, const int* in_sizes, int n_in,
                              void* d_out, int out_size, void* d_ws, size_t ws_size,
                              hipStream_t stream) {
    const float* nodeF   = (const float*)d_in[0];
    const int*   src     = (const int*)d_in[1];
    const int*   dst     = (const int*)d_in[2];
    // d_in[3] = graph_ids (implied by node index / NPG)
    const float* W       = (const float*)d_in[4];
    const float* gamma   = (const float*)d_in[5];
    const float* beta    = (const float*)d_in[6];
    const float* lambdas = (const float*)d_in[7];
    float* out = (float*)d_out;

    float* ws   = (float*)d_ws;
    float* cOut = ws;                                   // [NN]
    float* cIn  = cOut + NN;                            // [NN]
    float* Abuf = cIn + NN;                             // [BG*100*100]  41 MB
    float* bufH = Abuf + (size_t)BG*NPG*NPG;            // [NN*DD] fp32  210 MB
    float* mug  = bufH + (size_t)NN*DD;                 // [BG*DD]
    float* rsg  = mug  + (size_t)BG*DD;                 // [BG*DD]
    float* sumb = rsg  + (size_t)BG*DD;                 // [DD]
    float* sumq = sumb + DD;                            // [DD]
    unsigned short* msgHi = (unsigned short*)(sumq + DD);            // [NN*DD] bf16  105 MB
    unsigned short* msgLo = msgHi + (size_t)NN*DD;                   // [NN*DD] bf16  105 MB
    unsigned short* wHiT  = msgLo + (size_t)NN*DD;                   // [3*DD*DD]
    unsigned short* wLoT  = wHiT  + (size_t)3*DD*DD;                 // [3*DD*DD]

    hipMemsetAsync(cOut, 0, 2*(size_t)NN*sizeof(float), stream);
    hipMemsetAsync(Abuf, 0, (size_t)BG*NPG*NPG*sizeof(float), stream);
    k_degrees<<<EE/256, 256, 0, stream>>>(src, dst, cOut, cIn);
    k_deg_to_c<<<NN/256, 256, 0, stream>>>(cOut, cIn);
    k_build_A<<<EE/256, 256, 0, stream>>>(src, dst, Abuf);
    k_scale_A<<<(BG*NPG*NPG)/256, 256, 0, stream>>>(Abuf, cOut, cIn);
    k_prepW<<<192, 256, 0, stream>>>(W, wHiT, wLoT);

    const float* hcur = nodeF;
    for (int l = 0; l < 3; ++l) {
        k_graph_gemm<<<BG, 256, 0, stream>>>(Abuf, hcur, msgHi, msgLo);
        k_mfma_gemm<<<(NN/128)*(DD/128), 256, 0, stream>>>(
            msgHi, msgLo, wHiT + (size_t)l*DD*DD, wLoT + (size_t)l*DD*DD, bufH);
        hipMemsetAsync(sumb, 0, 2*DD*sizeof(float), stream);
        k_stats<<<BG, 256, 0, stream>>>(bufH, mug, rsg, sumb, sumq);
        k_norm<<<BG, 256, 0, stream>>>(bufH, mug, rsg, sumb, sumq,
                                       gamma + l*DD, beta + l*DD, lambdas + l*3, out, l);
        hcur = bufH;
    }
}